// Round 1
// baseline (272.917 us; speedup 1.0000x reference)
//
#include <hip/hip_runtime.h>

typedef _Float16 f16;
typedef _Float16 f16x8 __attribute__((ext_vector_type(8)));
typedef _Float16 f16x4 __attribute__((ext_vector_type(4)));
typedef float f32x4 __attribute__((ext_vector_type(4)));

#define NH 4
#define HD 256
#define BB 4
#define SS 2048
#define HID 1152
#define QKV_N 1536
#define ODIM (NH * HD)

// ---------------------------------------------------------------------------
// Transpose + fp32->fp16 convert:  dst[c][r] = (f16) src[r][c]
// grid: (C/32, R/32, batch), block 256
// ---------------------------------------------------------------------------
__global__ __launch_bounds__(256) void transpose_cvt(
    const float* __restrict__ src, long src_ld, long src_bs,
    f16* __restrict__ dst, long dst_ld, long dst_bs) {
  __shared__ float tile[32][33];
  src += (long)blockIdx.z * src_bs;
  dst += (long)blockIdx.z * dst_bs;
  int r0 = blockIdx.y * 32, c0 = blockIdx.x * 32;
  int tc = threadIdx.x & 31, tr = threadIdx.x >> 5;  // 32 cols x 8 rows
#pragma unroll
  for (int i = 0; i < 4; ++i)
    tile[tr + i * 8][tc] = src[(long)(r0 + tr + i * 8) * src_ld + c0 + tc];
  __syncthreads();
#pragma unroll
  for (int i = 0; i < 4; ++i)
    dst[(long)(c0 + tr + i * 8) * dst_ld + r0 + tc] = (f16)tile[tc][tr + i * 8];
}

// ---------------------------------------------------------------------------
// GEMM: C[M][N] fp32 = A[M][K] fp32  x  Bt[N][K] fp16   (B pre-transposed)
// 128x128 tile, BK=32, 4 waves (each 64x64 via 4x4 of 16x16x32 f16 MFMA)
// grid: (M/128, N/128), block 256
// ---------------------------------------------------------------------------
__global__ __launch_bounds__(256, 2) void gemm_a32_b16(
    const float* __restrict__ A, const f16* __restrict__ Bt,
    float* __restrict__ C, int K, int N) {
  __shared__ f16 As[128][40];  // pad 32 -> 40 halfs (80B stride: conflict-light)
  __shared__ f16 Bs[128][40];
  int tid = threadIdx.x;
  int wave = tid >> 6, lane = tid & 63;
  int l16 = lane & 15, lhi = lane >> 4;
  int wm = (wave >> 1) * 64, wn = (wave & 1) * 64;
  long bm = (long)blockIdx.x * 128, bn = (long)blockIdx.y * 128;
  f32x4 acc[4][4] = {};
  int a_kq = (tid & 7) * 4, a_r = tid >> 3;  // A: 4 floats each, rows a_r+32i
  int b_ko = (tid & 3) * 8, b_r = tid >> 2;  // B: 8 halfs each, rows b_r+64i

  for (int k0 = 0; k0 < K; k0 += 32) {
#pragma unroll
    for (int i = 0; i < 4; ++i) {
      int r = a_r + 32 * i;
      float4 v = *(const float4*)&A[(bm + r) * K + k0 + a_kq];
      f16x4 h = {(f16)v.x, (f16)v.y, (f16)v.z, (f16)v.w};
      *(f16x4*)&As[r][a_kq] = h;
    }
#pragma unroll
    for (int i = 0; i < 2; ++i) {
      int r = b_r + 64 * i;
      *(uint4*)&Bs[r][b_ko] = *(const uint4*)&Bt[(bn + r) * K + k0 + b_ko];
    }
    __syncthreads();
    f16x8 af[4], bf[4];
#pragma unroll
    for (int i = 0; i < 4; ++i)
      af[i] = *(const f16x8*)&As[wm + i * 16 + l16][lhi * 8];
#pragma unroll
    for (int j = 0; j < 4; ++j)
      bf[j] = *(const f16x8*)&Bs[wn + j * 16 + l16][lhi * 8];
#pragma unroll
    for (int i = 0; i < 4; ++i)
#pragma unroll
      for (int j = 0; j < 4; ++j)
        acc[i][j] = __builtin_amdgcn_mfma_f32_16x16x32_f16(af[i], bf[j], acc[i][j], 0, 0, 0);
    __syncthreads();
  }
  // epilogue: D[m][n]: m = lhi*4+reg, n = l16 (verified C/D layout)
#pragma unroll
  for (int i = 0; i < 4; ++i) {
    long row = bm + wm + i * 16 + lhi * 4;
#pragma unroll
    for (int r = 0; r < 4; ++r) {
      float* crow = C + (row + r) * N + bn + wn + l16;
#pragma unroll
      for (int j = 0; j < 4; ++j) crow[j * 16] = acc[i][j][r];
    }
  }
}

// ---------------------------------------------------------------------------
// RMSNorm + RoPE + scale, qkv fp32 -> Q/K fp16
// grid: (B*S), block 256. waves 0..3: q heads; wave 0 also does k.
// lane holds d = {l, l+64, l+128, l+192}; rope pairs (d, d+128).
// ---------------------------------------------------------------------------
__device__ __forceinline__ void norm_rope_store(
    const float* __restrict__ x, const float* __restrict__ w,
    const float* __restrict__ fc, const float* __restrict__ fs,
    f16* __restrict__ dst, float scale, int lane) {
  float x0 = x[lane], x1 = x[lane + 64], x2 = x[lane + 128], x3 = x[lane + 192];
  float ss = x0 * x0 + x1 * x1 + x2 * x2 + x3 * x3;
#pragma unroll
  for (int m = 1; m < 64; m <<= 1) ss += __shfl_xor(ss, m, 64);
  float inv = rsqrtf(ss * (1.0f / 256.0f) + 1e-6f);
  x0 *= inv * (1.0f + w[lane]);
  x1 *= inv * (1.0f + w[lane + 64]);
  x2 *= inv * (1.0f + w[lane + 128]);
  x3 *= inv * (1.0f + w[lane + 192]);
  float c0 = fc[lane], s0 = fs[lane], c1 = fc[lane + 64], s1 = fs[lane + 64];
  dst[lane]       = (f16)((x0 * c0 - x2 * s0) * scale);
  dst[lane + 64]  = (f16)((x1 * c1 - x3 * s1) * scale);
  dst[lane + 128] = (f16)((x0 * s0 + x2 * c0) * scale);
  dst[lane + 192] = (f16)((x1 * s1 + x3 * c1) * scale);
}

__global__ __launch_bounds__(256) void qkv_post(
    const float* __restrict__ qkv, const float* __restrict__ qnw,
    const float* __restrict__ knw, const float* __restrict__ fcos,
    const float* __restrict__ fsin, f16* __restrict__ Q, f16* __restrict__ Kb) {
  long row = blockIdx.x;  // b*2048 + s
  int b = (int)(row >> 11), s = (int)(row & 2047);
  int wave = threadIdx.x >> 6, lane = threadIdx.x & 63;
  const float* base = qkv + row * QKV_N;
  const float* fc = fcos + (long)s * 128;
  const float* fs = fsin + (long)s * 128;
  // q head `wave`, scaled by HD^-0.5
  norm_rope_store(base + wave * HD, qnw, fc, fs,
                  Q + ((long)(b * NH + wave) * SS + s) * HD, 0.0625f, lane);
  if (wave == 0)
    norm_rope_store(base + NH * HD, knw, fc, fs, Kb + row * HD, 1.0f, lane);
}

// ---------------------------------------------------------------------------
// Flash attention, causal, GQA (4 q heads share kv head 0).
// grid: (S/64, NH, B), block 256 (4 waves, each 16 q-rows). kv tile = 32.
// Q,K fp16 [.][s][256]; Vt fp16 [b][256][2048]; O fp32 [b*s][h*256].
// ---------------------------------------------------------------------------
__global__ __launch_bounds__(256, 2) void attn_fwd(
    const f16* __restrict__ Q, const f16* __restrict__ Kb,
    const f16* __restrict__ Vt, float* __restrict__ O) {
  __shared__ f16 Klds[32][264];      // [kv][d], pad 256->264
  __shared__ f16 Vlds[256][40];      // [d][kv], pad 32->40
  __shared__ f16 Plds[4][16][40];    // per-wave P tile [q][kv]
  int qb = blockIdx.x, h = blockIdx.y, b = blockIdx.z;
  int tid = threadIdx.x, wave = tid >> 6, lane = tid & 63;
  int l16 = lane & 15, lhi = lane >> 4;
  int q0 = qb * 64 + wave * 16;

  // Q fragments for all 8 k-steps (K dim = 256)
  f16x8 qf[8];
  const f16* Qbase = Q + ((long)(b * NH + h) * SS + q0 + l16) * HD + lhi * 8;
#pragma unroll
  for (int kb = 0; kb < 8; ++kb) qf[kb] = *(const f16x8*)(Qbase + kb * 32);

  f32x4 o[16] = {};
  float m_i[4] = {-1e30f, -1e30f, -1e30f, -1e30f};
  float l_i[4] = {0.f, 0.f, 0.f, 0.f};
  const f16* Kg = Kb + (long)b * SS * HD;
  const f16* Vg = Vt + (long)b * HD * SS;
  int ntiles = qb * 2 + 2;

  for (int t = 0; t < ntiles; ++t) {
    int kv0 = t * 32;
    __syncthreads();
    {  // stage K tile [32][256]
      int c8 = (tid & 31) * 8, r = tid >> 5;
#pragma unroll
      for (int i = 0; i < 4; ++i)
        *(uint4*)&Klds[r + i * 8][c8] =
            *(const uint4*)(Kg + (long)(kv0 + r + i * 8) * HD + c8);
      // stage Vt tile [256][32]
      int c8v = (tid & 3) * 8, rv = tid >> 2;
#pragma unroll
      for (int i = 0; i < 4; ++i)
        *(uint4*)&Vlds[rv + i * 64][c8v] =
            *(const uint4*)(Vg + (long)(rv + i * 64) * SS + kv0 + c8v);
    }
    __syncthreads();

    // QK^T: 16x32 scores per wave
    f32x4 sc[2] = {};
#pragma unroll
    for (int kb = 0; kb < 8; ++kb) {
#pragma unroll
      for (int cf = 0; cf < 2; ++cf) {
        f16x8 bf = *(const f16x8*)&Klds[cf * 16 + l16][kb * 32 + lhi * 8];
        sc[cf] = __builtin_amdgcn_mfma_f32_16x16x32_f16(qf[kb], bf, sc[cf], 0, 0, 0);
      }
    }

    // causal mask + online softmax (fp32, in-register, 16-lane-group reduce)
    float p0[4], p1[4], scl[4];
#pragma unroll
    for (int r = 0; r < 4; ++r) {
      int q = q0 + lhi * 4 + r;
      float s0 = (kv0 + l16 <= q) ? sc[0][r] : -1e30f;
      float s1 = (kv0 + 16 + l16 <= q) ? sc[1][r] : -1e30f;
      float mx = fmaxf(s0, s1);
      mx = fmaxf(mx, __shfl_xor(mx, 1));
      mx = fmaxf(mx, __shfl_xor(mx, 2));
      mx = fmaxf(mx, __shfl_xor(mx, 4));
      mx = fmaxf(mx, __shfl_xor(mx, 8));
      float mn = fmaxf(m_i[r], mx);
      float sc_ = __expf(m_i[r] - mn);
      p0[r] = __expf(s0 - mn);
      p1[r] = __expf(s1 - mn);
      float rs = p0[r] + p1[r];
      rs += __shfl_xor(rs, 1);
      rs += __shfl_xor(rs, 2);
      rs += __shfl_xor(rs, 4);
      rs += __shfl_xor(rs, 8);
      l_i[r] = l_i[r] * sc_ + rs;
      m_i[r] = mn;
      scl[r] = sc_;
    }
#pragma unroll
    for (int nf = 0; nf < 16; ++nf)
#pragma unroll
      for (int r = 0; r < 4; ++r) o[nf][r] *= scl[r];

    // P -> fp16 A-fragment layout via per-wave LDS
#pragma unroll
    for (int r = 0; r < 4; ++r) {
      Plds[wave][lhi * 4 + r][l16] = (f16)p0[r];
      Plds[wave][lhi * 4 + r][16 + l16] = (f16)p1[r];
    }
    asm volatile("s_waitcnt lgkmcnt(0)" ::: "memory");
    f16x8 pa = *(const f16x8*)&Plds[wave][l16][lhi * 8];
#pragma unroll
    for (int nf = 0; nf < 16; ++nf) {
      f16x8 vf = *(const f16x8*)&Vlds[nf * 16 + l16][lhi * 8];
      o[nf] = __builtin_amdgcn_mfma_f32_16x16x32_f16(pa, vf, o[nf], 0, 0, 0);
    }
  }

  // epilogue: O[b*2048+s][h*256 + d]
#pragma unroll
  for (int r = 0; r < 4; ++r) {
    float invl = 1.0f / l_i[r];
    long srow = q0 + lhi * 4 + r;
    float* Orow = O + ((long)b * SS + srow) * ODIM + h * HD + l16;
#pragma unroll
    for (int nf = 0; nf < 16; ++nf) Orow[nf * 16] = o[nf][r] * invl;
  }
}

// ---------------------------------------------------------------------------
extern "C" void kernel_launch(void* const* d_in, const int* in_sizes, int n_in,
                              void* d_out, int out_size, void* d_ws, size_t ws_size,
                              hipStream_t stream) {
  const float* hidden = (const float*)d_in[0];  // [4][2048][1152]
  // d_in[1] = attention_mask (deterministic causal; handled analytically)
  const float* fcos = (const float*)d_in[2];    // [2048][128]
  const float* fsin = (const float*)d_in[3];
  const float* wqkv = (const float*)d_in[4];    // [1152][1536]
  const float* qnw = (const float*)d_in[5];     // [256]
  const float* knw = (const float*)d_in[6];
  const float* wo = (const float*)d_in[7];      // [1024][1152]
  float* out = (float*)d_out;                   // [8192][1152] fp32

  char* ws = (char*)d_ws;
  float* qkv = (float*)(ws + 0);                 // 50,331,648 B
  float* Obuf = (float*)(ws + 0);                // 33,554,432 B (reuses qkv)
  f16* Qb = (f16*)(ws + 50331648);               // 16,777,216 B
  f16* Kb = (f16*)(ws + 67108864);               //  4,194,304 B
  f16* Vt = (f16*)(ws + 71303168);               //  4,194,304 B
  f16* wqkvt = (f16*)(ws + 75497472);            //  3,538,944 B
  f16* wot = (f16*)(ws + 79036416);              //  2,359,296 B

  // weight transposes -> fp16 [N][K]
  transpose_cvt<<<dim3(QKV_N / 32, HID / 32, 1), 256, 0, stream>>>(
      wqkv, QKV_N, 0, wqkvt, HID, 0);
  transpose_cvt<<<dim3(HID / 32, ODIM / 32, 1), 256, 0, stream>>>(
      wo, HID, 0, wot, ODIM, 0);

  // QKV GEMM: [8192][1536] fp32
  gemm_a32_b16<<<dim3(BB * SS / 128, QKV_N / 128), 256, 0, stream>>>(
      hidden, wqkvt, qkv, HID, QKV_N);

  // RMSNorm + RoPE -> Q, K fp16
  qkv_post<<<dim3(BB * SS), 256, 0, stream>>>(qkv, qnw, knw, fcos, fsin, Qb, Kb);

  // V slice transpose: qkv[b][s][1280+d] -> Vt[b][d][s] fp16
  transpose_cvt<<<dim3(HD / 32, SS / 32, BB), 256, 0, stream>>>(
      qkv + 1280, QKV_N, (long)SS * QKV_N, Vt, SS, (long)HD * SS);

  // flash attention -> O fp32 [8192][1024]
  attn_fwd<<<dim3(SS / 64, NH, BB), 256, 0, stream>>>(Qb, Kb, Vt, Obuf);

  // output GEMM -> d_out
  gemm_a32_b16<<<dim3(BB * SS / 128, HID / 128), 256, 0, stream>>>(
      Obuf, wot, out, ODIM, HID);
}